// Round 1
// baseline (459.279 us; speedup 1.0000x reference)
//
#include <hip/hip_runtime.h>
#include <hip/hip_bf16.h>

// Workspace layout (float offsets)
#define WS_G_ITEM 0        // 4096 floats: item gram
#define WS_G_USER 4096     // 4096 floats: user gram
#define WS_SCAL   8192     // 4 floats: sum_pos, sum_pos2, ss_user, pad
#define WS_PART   8448     // per-block gram partials

__global__ void zero_scalars_kernel(float* scal) {
    if (threadIdx.x < 4) scal[threadIdx.x] = 0.0f;
}

// Gram of a tall [nrows x 64] matrix (optionally gathered by idx).
// Block = 256 threads = 4 waves. Each chunk = 32 rows staged in LDS;
// each wave takes 8 rows and accumulates the FULL 64x64 gram with an
// 8x8 register tile per lane. Per-block partial written to `partial`.
template<bool GATHER>
__global__ __launch_bounds__(256) void gram_kernel(
    const float* __restrict__ emb, const int* __restrict__ idx,
    int nrows, float* __restrict__ partial) {
    __shared__ float lds[32][64];
    __shared__ float g[4096];
    const int t = threadIdx.x;
    const int wave = t >> 6;
    const int lane = t & 63;
    const int r0 = (lane >> 3) * 8;
    const int c0 = (lane & 7) * 8;
    float acc[8][8];
#pragma unroll
    for (int i = 0; i < 8; ++i)
#pragma unroll
        for (int j = 0; j < 8; ++j) acc[i][j] = 0.0f;

    const int nchunks = (nrows + 31) >> 5;
    for (int ch = blockIdx.x; ch < nchunks; ch += gridDim.x) {
        const int base = ch * 32;
        __syncthreads();  // protect lds reads of previous chunk
#pragma unroll
        for (int i = 0; i < 2; ++i) {
            const int fi = t + i * 256;       // float4 slot 0..511
            const int r = fi >> 4;            // row in chunk
            const int cc = (fi & 15) * 4;     // col (float)
            const int row = base + r;
            float4 v = make_float4(0.f, 0.f, 0.f, 0.f);
            if (row < nrows) {
                const size_t rb = GATHER ? (size_t)idx[row] : (size_t)row;
                v = *reinterpret_cast<const float4*>(emb + rb * 64 + cc);
            }
            *reinterpret_cast<float4*>(&lds[r][cc]) = v;
        }
        __syncthreads();
#pragma unroll
        for (int rr = 0; rr < 8; ++rr) {
            const float* rowp = &lds[wave * 8 + rr][0];
            float a[8], b[8];
            *reinterpret_cast<float4*>(&a[0]) = *reinterpret_cast<const float4*>(rowp + r0);
            *reinterpret_cast<float4*>(&a[4]) = *reinterpret_cast<const float4*>(rowp + r0 + 4);
            *reinterpret_cast<float4*>(&b[0]) = *reinterpret_cast<const float4*>(rowp + c0);
            *reinterpret_cast<float4*>(&b[4]) = *reinterpret_cast<const float4*>(rowp + c0 + 4);
#pragma unroll
            for (int i = 0; i < 8; ++i)
#pragma unroll
                for (int j = 0; j < 8; ++j)
                    acc[i][j] = fmaf(a[i], b[j], acc[i][j]);
        }
    }
    // combine the 4 waves' grams into shared, then dump per-block partial
    for (int w = 0; w < 4; ++w) {
        __syncthreads();
        if (wave == w) {
#pragma unroll
            for (int i = 0; i < 8; ++i)
#pragma unroll
                for (int j = 0; j < 8; ++j) {
                    if (w == 0) g[(r0 + i) * 64 + c0 + j] = acc[i][j];
                    else        g[(r0 + i) * 64 + c0 + j] += acc[i][j];
                }
        }
    }
    __syncthreads();
    float* outp = partial + (size_t)blockIdx.x * 4096;
    for (int k = t; k < 4096; k += 256) outp[k] = g[k];
}

__global__ __launch_bounds__(256) void reduce_gram_kernel(
    const float* __restrict__ pa, int na, float* __restrict__ Gi,
    const float* __restrict__ pb, int nb, float* __restrict__ Gu) {
    const int e = blockIdx.x * 256 + threadIdx.x;
    if (e >= 4096) return;
    float s = 0.f;
    for (int b = 0; b < na; ++b) s += pa[(size_t)b * 4096 + e];
    Gi[e] = s;
    float s2 = 0.f;
    for (int b = 0; b < nb; ++b) s2 += pb[(size_t)b * 4096 + e];
    Gu[e] = s2;
}

__global__ __launch_bounds__(256) void sumsq_kernel(
    const float* __restrict__ x, int n4, float* __restrict__ outp) {
    float s = 0.f;
    for (int i = blockIdx.x * 256 + threadIdx.x; i < n4; i += gridDim.x * 256) {
        const float4 v = reinterpret_cast<const float4*>(x)[i];
        s = fmaf(v.x, v.x, s); s = fmaf(v.y, v.y, s);
        s = fmaf(v.z, v.z, s); s = fmaf(v.w, v.w, s);
    }
#pragma unroll
    for (int off = 32; off >= 1; off >>= 1) s += __shfl_xor(s, off, 64);
    __shared__ float r[4];
    if ((threadIdx.x & 63) == 0) r[threadIdx.x >> 6] = s;
    __syncthreads();
    if (threadIdx.x == 0) atomicAdd(outp, r[0] + r[1] + r[2] + r[3]);
}

// One block per batch element b. 16 lanes per item row (float4/lane),
// 16 items in flight per block iteration.
__global__ __launch_bounds__(256) void pos_kernel(
    const int* __restrict__ users, const int* __restrict__ hist,
    const float* __restrict__ user_emb, const float* __restrict__ item_emb,
    const float* __restrict__ Hw, int histL, float* __restrict__ scal) {
    const int b = blockIdx.x;
    const int iu = users[b];
    const int t = threadIdx.x;
    const int l16 = t & 15;
    const int grp = t >> 4;
    const float4 vu = *reinterpret_cast<const float4*>(user_emb + (size_t)iu * 64 + l16 * 4);
    const float4 vh = *reinterpret_cast<const float4*>(Hw + l16 * 4);
    const float4 uh = make_float4(vu.x * vh.x, vu.y * vh.y, vu.z * vh.z, vu.w * vh.w);
    __shared__ int hrow[256];
    if (t < histL) hrow[t] = hist[(size_t)iu * histL + t];
    __syncthreads();
    float s1 = 0.f, s2 = 0.f;
    for (int l = grp; l < histL; l += 16) {
        const float4 vi = *reinterpret_cast<const float4*>(item_emb + (size_t)hrow[l] * 64 + l16 * 4);
        float d = vi.x * uh.x + vi.y * uh.y + vi.z * uh.z + vi.w * uh.w;
        d += __shfl_xor(d, 1, 16);
        d += __shfl_xor(d, 2, 16);
        d += __shfl_xor(d, 4, 16);
        d += __shfl_xor(d, 8, 16);
        s1 += d;                 // duplicated 16x per item; scaled by 1/16 below
        s2 = fmaf(d, d, s2);
    }
#pragma unroll
    for (int off = 32; off >= 1; off >>= 1) {
        s1 += __shfl_xor(s1, off, 64);
        s2 += __shfl_xor(s2, off, 64);
    }
    __shared__ float r1[4], r2[4];
    if ((t & 63) == 0) { r1[t >> 6] = s1; r2[t >> 6] = s2; }
    __syncthreads();
    if (t == 0) {
        atomicAdd(scal + 0, (r1[0] + r1[1] + r1[2] + r1[3]) * 0.0625f);
        atomicAdd(scal + 1, (r2[0] + r2[1] + r2[2] + r2[3]) * 0.0625f);
    }
}

__global__ __launch_bounds__(256) void finalize_kernel(
    const float* __restrict__ Gi, const float* __restrict__ Gu,
    const float* __restrict__ Hw, const float* __restrict__ scal,
    float* __restrict__ outp) {
    const int t = threadIdx.x;
    float tsum = 0.f, trace = 0.f;
    for (int e = t; e < 4096; e += 256) {
        const int i = e >> 6, j = e & 63;
        const float gi = Gi[e];
        tsum += gi * Gu[e] * Hw[i] * Hw[j];
        if (i == j) trace += gi;
    }
#pragma unroll
    for (int off = 32; off >= 1; off >>= 1) {
        tsum += __shfl_xor(tsum, off, 64);
        trace += __shfl_xor(trace, off, 64);
    }
    __shared__ float rt[4], rr[4];
    if ((t & 63) == 0) { rt[t >> 6] = tsum; rr[t >> 6] = trace; }
    __syncthreads();
    if (t == 0) {
        const float tt = rt[0] + rt[1] + rt[2] + rt[3];
        const float tr = rr[0] + rr[1] + rr[2] + rr[3];
        const float reg = 1e-4f * (sqrtf(scal[2]) + sqrtf(tr));
        const float loss = 0.5f * tt + 0.5f * scal[1] - 2.0f * scal[0] + reg;
        outp[0] = loss; outp[1] = reg; outp[2] = reg;
    }
}

extern "C" void kernel_launch(void* const* d_in, const int* in_sizes, int n_in,
                              void* d_out, int out_size, void* d_ws, size_t ws_size,
                              hipStream_t stream) {
    const int*   users    = (const int*)d_in[0];
    const int*   hist     = (const int*)d_in[1];
    const float* user_emb = (const float*)d_in[2];
    const float* item_emb = (const float*)d_in[3];
    const float* Hw       = (const float*)d_in[4];
    float* outp = (float*)d_out;
    float* ws   = (float*)d_ws;

    const int n_users = in_sizes[2] / 64;            // 200000
    const int n_items = in_sizes[3] / 64;            // 1000000
    const int batch   = in_sizes[0];                 // 4096
    const int histL   = in_sizes[1] / n_users;       // 200

    const int NB_USER = 8;
    long avail = (long)(ws_size / 4) - WS_PART;
    int nbA = (int)((avail - (long)NB_USER * 4096) / 4096);
    if (nbA > 512) nbA = 512;
    if (nbA < 1) nbA = 1;
    float* partA = ws + WS_PART;
    float* partB = partA + (size_t)nbA * 4096;

    zero_scalars_kernel<<<1, 64, 0, stream>>>(ws + WS_SCAL);
    gram_kernel<false><<<nbA, 256, 0, stream>>>(item_emb, nullptr, n_items, partA);
    gram_kernel<true><<<NB_USER, 256, 0, stream>>>(user_emb, users, batch, partB);
    reduce_gram_kernel<<<16, 256, 0, stream>>>(partA, nbA, ws + WS_G_ITEM,
                                               partB, NB_USER, ws + WS_G_USER);
    sumsq_kernel<<<2048, 256, 0, stream>>>(user_emb, in_sizes[2] / 4, ws + WS_SCAL + 2);
    pos_kernel<<<batch, 256, 0, stream>>>(users, hist, user_emb, item_emb, Hw, histL,
                                          ws + WS_SCAL);
    finalize_kernel<<<1, 256, 0, stream>>>(ws + WS_G_ITEM, ws + WS_G_USER, Hw,
                                           ws + WS_SCAL, outp);
}

// Round 2
// 326.069 us; speedup vs baseline: 1.4085x; 1.4085x over previous
//
#include <hip/hip_runtime.h>
#include <hip/hip_bf16.h>

typedef __bf16 bf16x8 __attribute__((ext_vector_type(8)));
typedef float f32x16 __attribute__((ext_vector_type(16)));

// Workspace layout (float offsets)
#define WS_GI   0          // 3072 floats: item gram tiles G00|G01|G11 (32x32 each)
#define WS_GU   3072       // 3072 floats: user gram tiles
#define WS_SCAL 6144       // 4 floats: sum_pos, sum_pos2, ss_user, pad

__global__ __launch_bounds__(256) void zero_ws_kernel(float* ws, int n) {
    const int i = blockIdx.x * 256 + threadIdx.x;
    if (i < n) ws[i] = 0.0f;
}

// Gram of tall [nrows x 64] matrix (optionally gathered rows) via bf16 MFMA.
// Each wave owns disjoint 16-row K-slices; lane l reads column (lane&31) /
// (lane&31)+32 of rows k0+(lane>>5)*8+j  -> fragments feed A and B of
// mfma_f32_32x32x16_bf16 directly (no LDS staging).
// Output: 3 tiles (G00, G01, G11); G10 = G01^T handled in finalize.
template<bool GATHER>
__global__ __launch_bounds__(256) void gram_mfma_kernel(
    const float* __restrict__ emb, const int* __restrict__ idx,
    int nrows, int nwaves_total, float* __restrict__ G) {
    const int t = threadIdx.x;
    const int lane = t & 63;
    const int wave = t >> 6;
    const int c = lane & 31;
    const int kh = lane >> 5;
    const int wid = blockIdx.x * 4 + wave;

    f32x16 g00 = {}, g01 = {}, g11 = {};

    for (int k0 = wid * 16; k0 < nrows; k0 += nwaves_total * 16) {
        const int kbase = k0 + kh * 8;
        bf16x8 f0, f1;
#pragma unroll
        for (int j = 0; j < 8; ++j) {
            const int r = kbase + j;
            float a = 0.0f, b = 0.0f;
            if (r < nrows) {
                const size_t rb = (GATHER ? (size_t)idx[r] : (size_t)r) * 64;
                a = emb[rb + c];
                b = emb[rb + 32 + c];
            }
            f0[j] = (__bf16)a;
            f1[j] = (__bf16)b;
        }
        g00 = __builtin_amdgcn_mfma_f32_32x32x16_bf16(f0, f0, g00, 0, 0, 0);
        g01 = __builtin_amdgcn_mfma_f32_32x32x16_bf16(f0, f1, g01, 0, 0, 0);
        g11 = __builtin_amdgcn_mfma_f32_32x32x16_bf16(f1, f1, g11, 0, 0, 0);
    }

    // Block-level reduce in LDS (atomic), then one global atomicAdd per cell.
    __shared__ float red[3072];
    for (int i = t; i < 3072; i += 256) red[i] = 0.0f;
    __syncthreads();
#pragma unroll
    for (int r = 0; r < 16; ++r) {
        const int row = (r & 3) + 8 * (r >> 2) + 4 * kh;
        const int cell = row * 32 + c;
        atomicAdd(&red[cell], g00[r]);
        atomicAdd(&red[1024 + cell], g01[r]);
        atomicAdd(&red[2048 + cell], g11[r]);
    }
    __syncthreads();
    for (int i = t; i < 3072; i += 256) atomicAdd(&G[i], red[i]);
}

__global__ __launch_bounds__(256) void sumsq_kernel(
    const float* __restrict__ x, int n4, float* __restrict__ outp) {
    float s = 0.f;
    for (int i = blockIdx.x * 256 + threadIdx.x; i < n4; i += gridDim.x * 256) {
        const float4 v = reinterpret_cast<const float4*>(x)[i];
        s = fmaf(v.x, v.x, s); s = fmaf(v.y, v.y, s);
        s = fmaf(v.z, v.z, s); s = fmaf(v.w, v.w, s);
    }
#pragma unroll
    for (int off = 32; off >= 1; off >>= 1) s += __shfl_xor(s, off, 64);
    __shared__ float r[4];
    if ((threadIdx.x & 63) == 0) r[threadIdx.x >> 6] = s;
    __syncthreads();
    if (threadIdx.x == 0) atomicAdd(outp, r[0] + r[1] + r[2] + r[3]);
}

// One block per batch element. 16 lanes per item row; 4-deep ILP unroll so
// 16 independent gathered float4 loads are in flight per wave.
__global__ __launch_bounds__(256) void pos_kernel(
    const int* __restrict__ users, const int* __restrict__ hist,
    const float* __restrict__ user_emb, const float* __restrict__ item_emb,
    const float* __restrict__ Hw, int histL, float* __restrict__ scal) {
    const int b = blockIdx.x;
    const int iu = users[b];
    const int t = threadIdx.x;
    const int l16 = t & 15;
    const int grp = t >> 4;
    const float4 vu = *reinterpret_cast<const float4*>(user_emb + (size_t)iu * 64 + l16 * 4);
    const float4 vh = *reinterpret_cast<const float4*>(Hw + l16 * 4);
    const float4 uh = make_float4(vu.x * vh.x, vu.y * vh.y, vu.z * vh.z, vu.w * vh.w);
    __shared__ int hrow[256];
    if (t < histL) hrow[t] = hist[(size_t)iu * histL + t];
    __syncthreads();

    float s1 = 0.f, s2 = 0.f;
    int l = grp;
    for (; l + 48 < histL; l += 64) {
        float pd[4];
#pragma unroll
        for (int u4 = 0; u4 < 4; ++u4) {
            const float4 vi = *reinterpret_cast<const float4*>(
                item_emb + (size_t)hrow[l + u4 * 16] * 64 + l16 * 4);
            pd[u4] = vi.x * uh.x + vi.y * uh.y + vi.z * uh.z + vi.w * uh.w;
        }
#pragma unroll
        for (int u4 = 0; u4 < 4; ++u4) {
            s1 += pd[u4];                      // per-lane partial; reduced once at end
            float d = pd[u4];
            d += __shfl_xor(d, 1, 16);
            d += __shfl_xor(d, 2, 16);
            d += __shfl_xor(d, 4, 16);
            d += __shfl_xor(d, 8, 16);
            s2 = fmaf(d, d, s2);               // replicated 16x; scaled below
        }
    }
    for (; l < histL; l += 16) {
        const float4 vi = *reinterpret_cast<const float4*>(
            item_emb + (size_t)hrow[l] * 64 + l16 * 4);
        float pd = vi.x * uh.x + vi.y * uh.y + vi.z * uh.z + vi.w * uh.w;
        s1 += pd;
        float d = pd;
        d += __shfl_xor(d, 1, 16);
        d += __shfl_xor(d, 2, 16);
        d += __shfl_xor(d, 4, 16);
        d += __shfl_xor(d, 8, 16);
        s2 = fmaf(d, d, s2);
    }
#pragma unroll
    for (int off = 32; off >= 1; off >>= 1) {
        s1 += __shfl_xor(s1, off, 64);
        s2 += __shfl_xor(s2, off, 64);
    }
    __shared__ float r1[4], r2[4];
    if ((t & 63) == 0) { r1[t >> 6] = s1; r2[t >> 6] = s2; }
    __syncthreads();
    if (t == 0) {
        atomicAdd(scal + 0, r1[0] + r1[1] + r1[2] + r1[3]);
        atomicAdd(scal + 1, (r2[0] + r2[1] + r2[2] + r2[3]) * 0.0625f);
    }
}

__global__ __launch_bounds__(256) void finalize_kernel(
    const float* __restrict__ Gi, const float* __restrict__ Gu,
    const float* __restrict__ Hw, const float* __restrict__ scal,
    float* __restrict__ outp) {
    const int t = threadIdx.x;
    float tsum = 0.f, trace = 0.f;
    for (int e = t; e < 3072; e += 256) {
        const int tile = e >> 10;
        const int r = (e & 1023) >> 5;
        const int cc = e & 31;
        const int i = (tile == 2) ? r + 32 : r;
        const int j = (tile == 0) ? cc : cc + 32;
        const float w = (tile == 1) ? 2.0f : 1.0f;
        const float gi = Gi[e];
        tsum += w * gi * Gu[e] * Hw[i] * Hw[j];
        if (i == j) trace += gi;
    }
#pragma unroll
    for (int off = 32; off >= 1; off >>= 1) {
        tsum += __shfl_xor(tsum, off, 64);
        trace += __shfl_xor(trace, off, 64);
    }
    __shared__ float rt[4], rr[4];
    if ((t & 63) == 0) { rt[t >> 6] = tsum; rr[t >> 6] = trace; }
    __syncthreads();
    if (t == 0) {
        const float tt = rt[0] + rt[1] + rt[2] + rt[3];
        const float tr = rr[0] + rr[1] + rr[2] + rr[3];
        const float reg = 1e-4f * (sqrtf(scal[2]) + sqrtf(tr));
        const float loss = 0.5f * tt + 0.5f * scal[1] - 2.0f * scal[0] + reg;
        outp[0] = loss; outp[1] = reg; outp[2] = reg;
    }
}

extern "C" void kernel_launch(void* const* d_in, const int* in_sizes, int n_in,
                              void* d_out, int out_size, void* d_ws, size_t ws_size,
                              hipStream_t stream) {
    const int*   users    = (const int*)d_in[0];
    const int*   hist     = (const int*)d_in[1];
    const float* user_emb = (const float*)d_in[2];
    const float* item_emb = (const float*)d_in[3];
    const float* Hw       = (const float*)d_in[4];
    float* outp = (float*)d_out;
    float* ws   = (float*)d_ws;

    const int n_users = in_sizes[2] / 64;            // 200000
    const int n_items = in_sizes[3] / 64;            // 1000000
    const int batch   = in_sizes[0];                 // 4096
    const int histL   = in_sizes[1] / n_users;       // 200

    const int NB_ITEM = 1024;
    const int NB_USER = 16;

    zero_ws_kernel<<<(6160 + 255) / 256, 256, 0, stream>>>(ws, 6148);
    gram_mfma_kernel<false><<<NB_ITEM, 256, 0, stream>>>(
        item_emb, nullptr, n_items, NB_ITEM * 4, ws + WS_GI);
    gram_mfma_kernel<true><<<NB_USER, 256, 0, stream>>>(
        user_emb, users, batch, NB_USER * 4, ws + WS_GU);
    sumsq_kernel<<<2048, 256, 0, stream>>>(user_emb, in_sizes[2] / 4, ws + WS_SCAL + 2);
    pos_kernel<<<batch, 256, 0, stream>>>(users, hist, user_emb, item_emb, Hw, histL,
                                          ws + WS_SCAL);
    finalize_kernel<<<1, 256, 0, stream>>>(ws + WS_GI, ws + WS_GU, Hw,
                                           ws + WS_SCAL, outp);
}

// Round 3
// 179.641 us; speedup vs baseline: 2.5567x; 1.8151x over previous
//
#include <hip/hip_runtime.h>
#include <hip/hip_bf16.h>

typedef __bf16 bf16x8 __attribute__((ext_vector_type(8)));
typedef float f32x16 __attribute__((ext_vector_type(16)));

#define AS1 __attribute__((address_space(1)))
#define AS3 __attribute__((address_space(3)))

static __device__ __forceinline__ void gld_lds16(const float* g, float* l) {
    __builtin_amdgcn_global_load_lds((const AS1 void*)g, (AS3 void*)l, 16, 0, 0);
}

// ---------------- Gram (G = E^T E over [nrows x 64], optional row gather) ----
// 128 threads (2 waves). Tile = 32 rows staged to LDS via global_load_lds
// width=16 (4 rounds x 2KB), double-buffered with counted vmcnt + raw
// barriers. Wave w computes 16-row K-step: 3 MFMAs (G00,G01,G11 32x32 tiles).
// Per-block partial (3072 floats) written plain; no atomics anywhere.
template<bool GATHER>
__global__ __launch_bounds__(128) void gram_kernel(
    const float* __restrict__ emb, const int* __restrict__ idx,
    int nrows, int ntiles, int nblocks, float* __restrict__ partial) {
    __shared__ float lds[2][32][64];
    const int t = threadIdx.x;
    const int wave = t >> 6, lane = t & 63;
    const int kh = lane >> 5, c = lane & 31;

    auto stage = [&](int tile, int buf) {
#pragma unroll
        for (int r = 0; r < 4; ++r) {
            const int rl = r * 8 + (t >> 4);           // row within tile
            int rg = tile * 32 + rl;
            if (rg >= nrows) rg = nrows - 1;           // clamp; zeroed at compute
            const size_t row = GATHER ? (size_t)idx[rg] : (size_t)rg;
            const float* src = emb + row * 64 + (t & 15) * 4;
            float* dst = &lds[buf][r * 8 + wave * 4][0];   // wave-uniform base
            gld_lds16(src, dst);
        }
    };

    f32x16 g00 = {}, g01 = {}, g11 = {};
    int tile = blockIdx.x;
    if (tile < ntiles) stage(tile, 0);
    if (tile + nblocks < ntiles) stage(tile + nblocks, 1);
    int buf = 0;
    for (; tile < ntiles; tile += nblocks, buf ^= 1) {
        if (!GATHER && tile + nblocks < ntiles) {
            asm volatile("s_waitcnt vmcnt(4)" ::: "memory");
        } else {
            asm volatile("s_waitcnt vmcnt(0)" ::: "memory");
        }
        __builtin_amdgcn_s_barrier();
        // compute this wave's 16-row K-step from LDS
        {
            const int kb = wave * 16 + kh * 8;
            bf16x8 f0, f1;
            if (tile * 32 + 32 <= nrows) {
#pragma unroll
                for (int j = 0; j < 8; ++j) {
                    f0[j] = (__bf16)lds[buf][kb + j][c];
                    f1[j] = (__bf16)lds[buf][kb + j][c + 32];
                }
            } else {
#pragma unroll
                for (int j = 0; j < 8; ++j) {
                    const bool ok = (tile * 32 + kb + j) < nrows;
                    f0[j] = (__bf16)(ok ? lds[buf][kb + j][c] : 0.0f);
                    f1[j] = (__bf16)(ok ? lds[buf][kb + j][c + 32] : 0.0f);
                }
            }
            g00 = __builtin_amdgcn_mfma_f32_32x32x16_bf16(f0, f0, g00, 0, 0, 0);
            g01 = __builtin_amdgcn_mfma_f32_32x32x16_bf16(f0, f1, g01, 0, 0, 0);
            g11 = __builtin_amdgcn_mfma_f32_32x32x16_bf16(f1, f1, g11, 0, 0, 0);
        }
        __builtin_amdgcn_s_barrier();
        if (tile + 2 * nblocks < ntiles) stage(tile + 2 * nblocks, buf);
    }

    // combine the 2 waves in LDS, write one plain partial per block
    __syncthreads();
    float* red = &lds[0][0][0];
    if (wave == 0) {
#pragma unroll
        for (int r = 0; r < 16; ++r) {
            const int cell = ((r & 3) + 8 * (r >> 2) + 4 * kh) * 32 + c;
            red[cell] = g00[r]; red[1024 + cell] = g01[r]; red[2048 + cell] = g11[r];
        }
    }
    __syncthreads();
    if (wave == 1) {
#pragma unroll
        for (int r = 0; r < 16; ++r) {
            const int cell = ((r & 3) + 8 * (r >> 2) + 4 * kh) * 32 + c;
            red[cell] += g00[r]; red[1024 + cell] += g01[r]; red[2048 + cell] += g11[r];
        }
    }
    __syncthreads();
    float* outp = partial + (size_t)blockIdx.x * 3072;
    for (int i = t; i < 3072; i += 128) outp[i] = red[i];
}

__global__ __launch_bounds__(256) void reduce_gram_kernel(
    const float* __restrict__ pa, int na, float* __restrict__ GI,
    const float* __restrict__ pb, int nb, float* __restrict__ GU) {
    const int e = blockIdx.x * 256 + threadIdx.x;   // grid 24 -> 6144
    const float* p; float* dst; int n, ee;
    if (e < 3072)      { p = pa; dst = GI; n = na; ee = e; }
    else if (e < 6144) { p = pb; dst = GU; n = nb; ee = e - 3072; }
    else return;
    float s[8] = {0.f,0.f,0.f,0.f,0.f,0.f,0.f,0.f};
    int b = 0;
    for (; b + 8 <= n; b += 8)
#pragma unroll
        for (int u = 0; u < 8; ++u) s[u] += p[(size_t)(b + u) * 3072 + ee];
    for (; b < n; ++b) s[0] += p[(size_t)b * 3072 + ee];
    dst[ee] = ((s[0]+s[1])+(s[2]+s[3])) + ((s[4]+s[5])+(s[6]+s[7]));
}

__global__ __launch_bounds__(256) void sumsq_kernel(
    const float* __restrict__ x, int n4, float* __restrict__ part) {
    float s = 0.f;
    for (int i = blockIdx.x * 256 + threadIdx.x; i < n4; i += gridDim.x * 256) {
        const float4 v = reinterpret_cast<const float4*>(x)[i];
        s = fmaf(v.x, v.x, s); s = fmaf(v.y, v.y, s);
        s = fmaf(v.z, v.z, s); s = fmaf(v.w, v.w, s);
    }
#pragma unroll
    for (int off = 32; off >= 1; off >>= 1) s += __shfl_xor(s, off, 64);
    __shared__ float r[4];
    if ((threadIdx.x & 63) == 0) r[threadIdx.x >> 6] = s;
    __syncthreads();
    if (threadIdx.x == 0) part[blockIdx.x] = r[0] + r[1] + r[2] + r[3];
}

// One block per batch element; each thread owns one history item: 16
// independent float4 loads of its row, dot with u*h held in registers.
__global__ __launch_bounds__(256) void pos_kernel(
    const int* __restrict__ users, const int* __restrict__ hist,
    const float* __restrict__ user_emb, const float* __restrict__ item_emb,
    const float* __restrict__ Hw, int histL,
    float* __restrict__ p1, float* __restrict__ p2) {
    const int b = blockIdx.x, t = threadIdx.x;
    const int iu = users[b];
    __shared__ float4 uh4[16];
    if (t < 16) {
        const float4 vu = *reinterpret_cast<const float4*>(user_emb + (size_t)iu * 64 + t * 4);
        const float4 vh = *reinterpret_cast<const float4*>(Hw + t * 4);
        uh4[t] = make_float4(vu.x*vh.x, vu.y*vh.y, vu.z*vh.z, vu.w*vh.w);
    }
    __syncthreads();
    float4 uh[16];
#pragma unroll
    for (int k = 0; k < 16; ++k) uh[k] = uh4[k];   // LDS broadcast -> regs

    float s1 = 0.f, s2 = 0.f;
    for (int l = t; l < histL; l += 256) {
        const int it = hist[(size_t)iu * histL + l];
        const float* ip = item_emb + (size_t)it * 64;
        float4 v[16];
#pragma unroll
        for (int k = 0; k < 16; ++k) v[k] = reinterpret_cast<const float4*>(ip)[k];
        float d = 0.f;
#pragma unroll
        for (int k = 0; k < 16; ++k) {
            d = fmaf(v[k].x, uh[k].x, d); d = fmaf(v[k].y, uh[k].y, d);
            d = fmaf(v[k].z, uh[k].z, d); d = fmaf(v[k].w, uh[k].w, d);
        }
        s1 += d;
        s2 = fmaf(d, d, s2);
    }
#pragma unroll
    for (int off = 32; off >= 1; off >>= 1) {
        s1 += __shfl_xor(s1, off, 64);
        s2 += __shfl_xor(s2, off, 64);
    }
    __shared__ float r1[4], r2[4];
    if ((t & 63) == 0) { r1[t >> 6] = s1; r2[t >> 6] = s2; }
    __syncthreads();
    if (t == 0) {
        p1[b] = r1[0] + r1[1] + r1[2] + r1[3];
        p2[b] = r2[0] + r2[1] + r2[2] + r2[3];
    }
}

__global__ __launch_bounds__(256) void finalize_kernel(
    const float* __restrict__ GI, const float* __restrict__ GU,
    const float* __restrict__ Hw,
    const float* __restrict__ p1, const float* __restrict__ p2, int npos,
    const float* __restrict__ ssq, int nss, float* __restrict__ outp) {
    const int t = threadIdx.x;
    float tsum = 0.f, trace = 0.f, s1 = 0.f, s2 = 0.f, su = 0.f;
    for (int e = t; e < 3072; e += 256) {
        const int tile = e >> 10, r = (e & 1023) >> 5, cc = e & 31;
        const int i = (tile == 2) ? r + 32 : r;
        const int j = (tile == 0) ? cc : cc + 32;
        const float w = (tile == 1) ? 2.0f : 1.0f;
        const float gi = GI[e];
        tsum += w * gi * GU[e] * Hw[i] * Hw[j];
        if (i == j) trace += gi;
    }
    for (int e = t; e < npos; e += 256) { s1 += p1[e]; s2 += p2[e]; }
    for (int e = t; e < nss; e += 256) su += ssq[e];
#pragma unroll
    for (int off = 32; off >= 1; off >>= 1) {
        tsum += __shfl_xor(tsum, off, 64);
        trace += __shfl_xor(trace, off, 64);
        s1 += __shfl_xor(s1, off, 64);
        s2 += __shfl_xor(s2, off, 64);
        su += __shfl_xor(su, off, 64);
    }
    __shared__ float rr[4][5];
    if ((t & 63) == 0) {
        rr[t >> 6][0] = tsum; rr[t >> 6][1] = trace; rr[t >> 6][2] = s1;
        rr[t >> 6][3] = s2;   rr[t >> 6][4] = su;
    }
    __syncthreads();
    if (t == 0) {
        const float tt = rr[0][0] + rr[1][0] + rr[2][0] + rr[3][0];
        const float tr = rr[0][1] + rr[1][1] + rr[2][1] + rr[3][1];
        const float a1 = rr[0][2] + rr[1][2] + rr[2][2] + rr[3][2];
        const float a2 = rr[0][3] + rr[1][3] + rr[2][3] + rr[3][3];
        const float au = rr[0][4] + rr[1][4] + rr[2][4] + rr[3][4];
        const float reg = 1e-4f * (sqrtf(au) + sqrtf(tr));
        const float loss = 0.5f * tt + 0.5f * a2 - 2.0f * a1 + reg;
        outp[0] = loss; outp[1] = reg; outp[2] = reg;
    }
}

extern "C" void kernel_launch(void* const* d_in, const int* in_sizes, int n_in,
                              void* d_out, int out_size, void* d_ws, size_t ws_size,
                              hipStream_t stream) {
    const int*   users    = (const int*)d_in[0];
    const int*   hist     = (const int*)d_in[1];
    const float* user_emb = (const float*)d_in[2];
    const float* item_emb = (const float*)d_in[3];
    const float* Hw       = (const float*)d_in[4];
    float* outp = (float*)d_out;
    float* ws   = (float*)d_ws;

    const int n_users = in_sizes[2] / 64;            // 200000
    const int n_items = in_sizes[3] / 64;            // 1000000
    const int batch   = in_sizes[0];                 // 4096
    const int histL   = in_sizes[1] / n_users;       // 200

    const int ntilesA = (n_items + 31) / 32;
    const int ntilesU = (batch + 31) / 32;
    int nbU = 64; if (nbU > ntilesU) nbU = ntilesU;
    const int NSS = 2048;

    // dynamic ws layout (floats)
    const size_t o_gi = 0, o_gu = 3072, o_p1 = 6144;
    const size_t o_p2 = o_p1 + (size_t)batch;
    const size_t o_ss = o_p2 + (size_t)batch;
    const size_t o_part = o_ss + NSS;
    long availf = (long)(ws_size / 4) - (long)o_part - (long)nbU * 3072;
    int nbA = (int)(availf / 3072);
    if (nbA > 1024) nbA = 1024;
    if (nbA < 1) nbA = 1;
    float* partA = ws + o_part;
    float* partB = partA + (size_t)nbA * 3072;

    gram_kernel<false><<<nbA, 128, 0, stream>>>(item_emb, nullptr, n_items,
                                                ntilesA, nbA, partA);
    gram_kernel<true><<<nbU, 128, 0, stream>>>(user_emb, users, batch,
                                               ntilesU, nbU, partB);
    sumsq_kernel<<<NSS, 256, 0, stream>>>(user_emb, in_sizes[2] / 4, ws + o_ss);
    pos_kernel<<<batch, 256, 0, stream>>>(users, hist, user_emb, item_emb, Hw,
                                          histL, ws + o_p1, ws + o_p2);
    reduce_gram_kernel<<<24, 256, 0, stream>>>(partA, nbA, ws + o_gi,
                                               partB, nbU, ws + o_gu);
    finalize_kernel<<<1, 256, 0, stream>>>(ws + o_gi, ws + o_gu, Hw,
                                           ws + o_p1, ws + o_p2, batch,
                                           ws + o_ss, NSS, outp);
}

// Round 4
// 154.992 us; speedup vs baseline: 2.9632x; 1.1590x over previous
//
#include <hip/hip_runtime.h>
#include <hip/hip_bf16.h>

typedef __bf16 bf16x8 __attribute__((ext_vector_type(8)));
typedef float f32x16 __attribute__((ext_vector_type(16)));

#define AS1 __attribute__((address_space(1)))
#define AS3 __attribute__((address_space(3)))

static __device__ __forceinline__ void gld_lds16(const float* g, float* l) {
    __builtin_amdgcn_global_load_lds((const AS1 void*)g, (AS3 void*)l, 16, 0, 0);
}

// ---- role: Gram of [nrows x 64] (optional gather) via bf16 MFMA -------------
// 256 threads / 4 waves. Tile = 64 rows staged via global_load_lds width=16,
// double-buffered (counted vmcnt for the dense path). Wave w computes the
// 16-row K-step [w*16, w*16+16): 3 MFMAs -> G00,G01,G11 32x32 tiles.
template<bool GATHER>
static __device__ __forceinline__ void gram_role(
    const float* __restrict__ emb, const int* __restrict__ idx,
    int nrows, int ntiles, int nblocks, int bid,
    float* __restrict__ partial, float (*lds)[64][64], int t) {
    const int wave = t >> 6, lane = t & 63;
    const int kh = lane >> 5, c = lane & 31;

    auto stage = [&](int tile, int buf) {
#pragma unroll
        for (int r = 0; r < 4; ++r) {
            const int rl = r * 16 + (t >> 4);          // row within 64-row tile
            int rg = tile * 64 + rl;
            if (rg >= nrows) rg = nrows - 1;           // clamp; zeroed at compute
            const size_t row = GATHER ? (size_t)idx[rg] : (size_t)rg;
            const float* src = emb + row * 64 + (t & 15) * 4;
            float* dst = &lds[buf][r * 16 + wave * 4][0];   // wave-uniform base
            gld_lds16(src, dst);
        }
    };

    f32x16 g00 = {}, g01 = {}, g11 = {};
    int tile = bid;
    if (tile < ntiles) stage(tile, 0);
    if (tile + nblocks < ntiles) stage(tile + nblocks, 1);
    int buf = 0;
    for (; tile < ntiles; tile += nblocks, buf ^= 1) {
        if (!GATHER && tile + nblocks < ntiles) {
            asm volatile("s_waitcnt vmcnt(4)" ::: "memory");
        } else {
            asm volatile("s_waitcnt vmcnt(0)" ::: "memory");
        }
        __builtin_amdgcn_s_barrier();
        const int kb = wave * 16 + kh * 8;
        bf16x8 f0, f1;
        if (tile * 64 + 64 <= nrows) {
#pragma unroll
            for (int j = 0; j < 8; ++j) {
                f0[j] = (__bf16)lds[buf][kb + j][c];
                f1[j] = (__bf16)lds[buf][kb + j][c + 32];
            }
        } else {
#pragma unroll
            for (int j = 0; j < 8; ++j) {
                const bool ok = (tile * 64 + kb + j) < nrows;
                f0[j] = (__bf16)(ok ? lds[buf][kb + j][c] : 0.0f);
                f1[j] = (__bf16)(ok ? lds[buf][kb + j][c + 32] : 0.0f);
            }
        }
        g00 = __builtin_amdgcn_mfma_f32_32x32x16_bf16(f0, f0, g00, 0, 0, 0);
        g01 = __builtin_amdgcn_mfma_f32_32x32x16_bf16(f0, f1, g01, 0, 0, 0);
        g11 = __builtin_amdgcn_mfma_f32_32x32x16_bf16(f1, f1, g11, 0, 0, 0);
        __builtin_amdgcn_s_barrier();
        if (tile + 2 * nblocks < ntiles) stage(tile + 2 * nblocks, buf);
    }

    // combine 4 waves in LDS, write one plain partial per block (no atomics)
    __syncthreads();
    float* red = &lds[0][0][0];
    for (int w = 0; w < 4; ++w) {
        if (wave == w) {
#pragma unroll
            for (int r = 0; r < 16; ++r) {
                const int cell = ((r & 3) + 8 * (r >> 2) + 4 * kh) * 32 + c;
                if (w == 0) {
                    red[cell] = g00[r]; red[1024 + cell] = g01[r]; red[2048 + cell] = g11[r];
                } else {
                    red[cell] += g00[r]; red[1024 + cell] += g01[r]; red[2048 + cell] += g11[r];
                }
            }
        }
        __syncthreads();
    }
    float* outp = partial + (size_t)bid * 3072;
    for (int i = t; i < 3072; i += 256) outp[i] = red[i];
}

// ---- role: pos_score sums. Each thread owns one history item of the current
// user; u*h broadcast via LDS (bank-broadcast reads are free).
static __device__ __forceinline__ void pos_role(
    const int* __restrict__ users, const int* __restrict__ hist,
    const float* __restrict__ user_emb, const float* __restrict__ item_emb,
    const float* __restrict__ Hw, int batch, int histL, int pid, int NP,
    float* __restrict__ p1, float* __restrict__ p2, float (*lds)[64][64], int t) {
    float4* uh4 = reinterpret_cast<float4*>(&lds[0][0][0]);
    float s1 = 0.f, s2 = 0.f;
    for (int b = pid; b < batch; b += NP) {
        const int iu = users[b];
        __syncthreads();
        if (t < 16) {
            const float4 vu = *reinterpret_cast<const float4*>(user_emb + (size_t)iu * 64 + t * 4);
            const float4 vh = *reinterpret_cast<const float4*>(Hw + t * 4);
            uh4[t] = make_float4(vu.x * vh.x, vu.y * vh.y, vu.z * vh.z, vu.w * vh.w);
        }
        __syncthreads();
        if (t < histL) {
            const int it = hist[(size_t)iu * histL + t];
            const float* ip = item_emb + (size_t)it * 64;
            float d = 0.f;
#pragma unroll
            for (int half = 0; half < 2; ++half) {
                float4 v[8];
#pragma unroll
                for (int k = 0; k < 8; ++k)
                    v[k] = reinterpret_cast<const float4*>(ip)[half * 8 + k];
#pragma unroll
                for (int k = 0; k < 8; ++k) {
                    const float4 u = uh4[half * 8 + k];
                    d = fmaf(v[k].x, u.x, d); d = fmaf(v[k].y, u.y, d);
                    d = fmaf(v[k].z, u.z, d); d = fmaf(v[k].w, u.w, d);
                }
            }
            s1 += d;
            s2 = fmaf(d, d, s2);
        }
    }
#pragma unroll
    for (int off = 32; off >= 1; off >>= 1) {
        s1 += __shfl_xor(s1, off, 64);
        s2 += __shfl_xor(s2, off, 64);
    }
    __syncthreads();
    float* r = &lds[0][0][0];
    if ((t & 63) == 0) { r[t >> 6] = s1; r[4 + (t >> 6)] = s2; }
    __syncthreads();
    if (t == 0) {
        p1[pid] = r[0] + r[1] + r[2] + r[3];
        p2[pid] = r[4] + r[5] + r[6] + r[7];
    }
}

// ---- role: sum of squares of a flat f32 buffer -----------------------------
static __device__ __forceinline__ void sumsq_role(
    const float* __restrict__ x, int n4, int cid, int NC,
    float* __restrict__ pss, float (*lds)[64][64], int t) {
    float s = 0.f;
    for (int i = cid * 256 + t; i < n4; i += NC * 256) {
        const float4 v = reinterpret_cast<const float4*>(x)[i];
        s = fmaf(v.x, v.x, s); s = fmaf(v.y, v.y, s);
        s = fmaf(v.z, v.z, s); s = fmaf(v.w, v.w, s);
    }
#pragma unroll
    for (int off = 32; off >= 1; off >>= 1) s += __shfl_xor(s, off, 64);
    float* r = &lds[0][0][0];
    if ((t & 63) == 0) r[t >> 6] = s;
    __syncthreads();
    if (t == 0) pss[cid] = r[0] + r[1] + r[2] + r[3];
}

// ---- fused heavy kernel: block-role partition so the independent memory
// streams (item gram / pos gather / user sumsq / user gram) share HBM.
__global__ __launch_bounds__(256, 4) void fused_kernel(
    const int* __restrict__ users, const int* __restrict__ hist,
    const float* __restrict__ user_emb, const float* __restrict__ item_emb,
    const float* __restrict__ Hw,
    int n_users, int n_items, int batch, int histL,
    int NA, int NP, int NC, int ND,
    float* __restrict__ partA, float* __restrict__ partB,
    float* __restrict__ p1, float* __restrict__ p2, float* __restrict__ pss) {
    __shared__ float lds[2][64][64];   // 32 KB
    const int bid = blockIdx.x;
    const int t = threadIdx.x;
    if (bid < NA) {
        gram_role<false>(item_emb, nullptr, n_items, (n_items + 63) >> 6, NA, bid,
                         partA, lds, t);
    } else if (bid < NA + NP) {
        pos_role(users, hist, user_emb, item_emb, Hw, batch, histL,
                 bid - NA, NP, p1, p2, lds, t);
    } else if (bid < NA + NP + NC) {
        sumsq_role(user_emb, n_users * 16, bid - NA - NP, NC, pss, lds, t);
    } else {
        gram_role<true>(user_emb, users, batch, (batch + 63) >> 6, ND,
                        bid - NA - NP - NC, partB, lds, t);
    }
}

__global__ __launch_bounds__(256) void reduce_gram_kernel(
    const float* __restrict__ pa, int na, float* __restrict__ GI,
    const float* __restrict__ pb, int nb, float* __restrict__ GU) {
    const int e = blockIdx.x * 256 + threadIdx.x;   // grid 24 -> 6144
    const float* p; float* dst; int n, ee;
    if (e < 3072)      { p = pa; dst = GI; n = na; ee = e; }
    else if (e < 6144) { p = pb; dst = GU; n = nb; ee = e - 3072; }
    else return;
    float s[8] = {0.f,0.f,0.f,0.f,0.f,0.f,0.f,0.f};
    int b = 0;
    for (; b + 8 <= n; b += 8)
#pragma unroll
        for (int u = 0; u < 8; ++u) s[u] += p[(size_t)(b + u) * 3072 + ee];
    for (; b < n; ++b) s[0] += p[(size_t)b * 3072 + ee];
    dst[ee] = ((s[0]+s[1])+(s[2]+s[3])) + ((s[4]+s[5])+(s[6]+s[7]));
}

__global__ __launch_bounds__(256) void finalize_kernel(
    const float* __restrict__ GI, const float* __restrict__ GU,
    const float* __restrict__ Hw,
    const float* __restrict__ p1, const float* __restrict__ p2, int npos,
    const float* __restrict__ ssq, int nss, float* __restrict__ outp) {
    const int t = threadIdx.x;
    float tsum = 0.f, trace = 0.f, s1 = 0.f, s2 = 0.f, su = 0.f;
    for (int e = t; e < 3072; e += 256) {
        const int tile = e >> 10, r = (e & 1023) >> 5, cc = e & 31;
        const int i = (tile == 2) ? r + 32 : r;
        const int j = (tile == 0) ? cc : cc + 32;
        const float w = (tile == 1) ? 2.0f : 1.0f;
        const float gi = GI[e];
        tsum += w * gi * GU[e] * Hw[i] * Hw[j];
        if (i == j) trace += gi;
    }
    for (int e = t; e < npos; e += 256) { s1 += p1[e]; s2 += p2[e]; }
    for (int e = t; e < nss; e += 256) su += ssq[e];
#pragma unroll
    for (int off = 32; off >= 1; off >>= 1) {
        tsum += __shfl_xor(tsum, off, 64);
        trace += __shfl_xor(trace, off, 64);
        s1 += __shfl_xor(s1, off, 64);
        s2 += __shfl_xor(s2, off, 64);
        su += __shfl_xor(su, off, 64);
    }
    __shared__ float rr[4][5];
    if ((t & 63) == 0) {
        rr[t >> 6][0] = tsum; rr[t >> 6][1] = trace; rr[t >> 6][2] = s1;
        rr[t >> 6][3] = s2;   rr[t >> 6][4] = su;
    }
    __syncthreads();
    if (t == 0) {
        const float tt = rr[0][0] + rr[1][0] + rr[2][0] + rr[3][0];
        const float tr = rr[0][1] + rr[1][1] + rr[2][1] + rr[3][1];
        const float a1 = rr[0][2] + rr[1][2] + rr[2][2] + rr[3][2];
        const float a2 = rr[0][3] + rr[1][3] + rr[2][3] + rr[3][3];
        const float au = rr[0][4] + rr[1][4] + rr[2][4] + rr[3][4];
        const float reg = 1e-4f * (sqrtf(au) + sqrtf(tr));
        const float loss = 0.5f * tt + 0.5f * a2 - 2.0f * a1 + reg;
        outp[0] = loss; outp[1] = reg; outp[2] = reg;
    }
}

extern "C" void kernel_launch(void* const* d_in, const int* in_sizes, int n_in,
                              void* d_out, int out_size, void* d_ws, size_t ws_size,
                              hipStream_t stream) {
    const int*   users    = (const int*)d_in[0];
    const int*   hist     = (const int*)d_in[1];
    const float* user_emb = (const float*)d_in[2];
    const float* item_emb = (const float*)d_in[3];
    const float* Hw       = (const float*)d_in[4];
    float* outp = (float*)d_out;
    float* ws   = (float*)d_ws;

    const int n_users = in_sizes[2] / 64;            // 200000
    const int n_items = in_sizes[3] / 64;            // 1000000
    const int batch   = in_sizes[0];                 // 4096
    const int histL   = in_sizes[1] / n_users;       // 200

    // role partition: ~bytes-proportional (pos overweighted for random access)
    int NA = 488, NP = 440, NC = 88, ND = 8;         // sum = 1024 = 4 blocks/CU
    // ws layout (floats)
    const size_t o_gi = 0, o_gu = 3072, o_p1 = 6144, o_p2 = 7168, o_ss = 8192;
    const size_t o_part = 8704;
    long availf = (long)(ws_size / 4) - (long)o_part - (long)ND * 3072;
    if ((long)NA * 3072 > availf) {                  // shrink if ws is tight
        NA = (int)(availf / 3072);
        if (NA < 8) NA = 8;
    }
    float* partA = ws + o_part;
    float* partB = partA + (size_t)NA * 3072;

    fused_kernel<<<NA + NP + NC + ND, 256, 0, stream>>>(
        users, hist, user_emb, item_emb, Hw,
        n_users, n_items, batch, histL,
        NA, NP, NC, ND,
        partA, partB, ws + o_p1, ws + o_p2, ws + o_ss);
    reduce_gram_kernel<<<24, 256, 0, stream>>>(partA, NA, ws + o_gi,
                                               partB, ND, ws + o_gu);
    finalize_kernel<<<1, 256, 0, stream>>>(ws + o_gi, ws + o_gu, Hw,
                                           ws + o_p1, ws + o_p2, NP,
                                           ws + o_ss, NC, outp);
}